// Round 1
// baseline (244.968 us; speedup 1.0000x reference)
//
#include <hip/hip_runtime.h>
#include <stdint.h>

// ---------------------------------------------------------------------------
// Attention (QKV proj + masked softmax attention + out proj), MI355X gfx950.
// bf16 MFMA (16x16x32) with fp32 accumulate everywhere.
// ---------------------------------------------------------------------------

typedef float    f32x4  __attribute__((ext_vector_type(4)));
typedef __bf16   bf16x8 __attribute__((ext_vector_type(8)));
typedef unsigned short u16x8 __attribute__((ext_vector_type(8)));
typedef unsigned short ushort_t;

#define HEADS 16
#define HDIM  64
#define NTOK  2048
#define BATCH 2
#define DIN   1024
#define D3    3072
#define MTOT  4096   // BATCH*NTOK

__device__ __forceinline__ ushort_t f2bf(float x) {
  uint32_t u = __builtin_bit_cast(uint32_t, x);
  uint32_t r = (u + 0x7fffu + ((u >> 16) & 1u)) >> 16;
  return (ushort_t)r;
}
__device__ __forceinline__ float bf2f(ushort_t u) {
  return __builtin_bit_cast(float, (uint32_t)u << 16);
}

// global->LDS direct 16B load (CK-style address space casts).
__device__ __forceinline__ void gld_lds16(const void* g, void* l) {
  auto gp = reinterpret_cast<const __attribute__((address_space(1))) uint32_t*>(
      reinterpret_cast<uintptr_t>(g));
  auto lp = reinterpret_cast<__attribute__((address_space(3))) uint32_t*>(
      reinterpret_cast<uintptr_t>(l));
  __builtin_amdgcn_global_load_lds(gp, lp, 16, 0, 0);
}

// ---------------------------------------------------------------------------
// prep kernels
// ---------------------------------------------------------------------------
__global__ __launch_bounds__(256) void conv_bf16_kernel(
    const float* __restrict__ in, ushort_t* __restrict__ out, int n) {
  int i = (blockIdx.x * 256 + threadIdx.x) * 8;
  if (i >= n) return;
  float4 a = *(const float4*)(in + i);
  float4 b = *(const float4*)(in + i + 4);
  u16x8 v;
  v[0]=f2bf(a.x); v[1]=f2bf(a.y); v[2]=f2bf(a.z); v[3]=f2bf(a.w);
  v[4]=f2bf(b.x); v[5]=f2bf(b.y); v[6]=f2bf(b.z); v[7]=f2bf(b.w);
  *(u16x8*)(out + i) = v;
}

// in fp32 [R][C] -> out bf16 [C][R]   (R,C multiples of 64)
__global__ __launch_bounds__(256) void transpose_bf16_kernel(
    const float* __restrict__ in, ushort_t* __restrict__ out, int R, int C) {
  __shared__ float tile[64][65];
  const int r0 = blockIdx.y * 64, c0 = blockIdx.x * 64;
  const int t = threadIdx.x;
#pragma unroll
  for (int it = 0; it < 4; ++it) {
    int r = it * 16 + (t >> 4);
    int c = (t & 15) * 4;
    float4 v = *(const float4*)(in + (size_t)(r0 + r) * C + c0 + c);
    tile[r][c] = v.x; tile[r][c+1] = v.y; tile[r][c+2] = v.z; tile[r][c+3] = v.w;
  }
  __syncthreads();
#pragma unroll
  for (int it = 0; it < 2; ++it) {
    int idx = it * 2048 + t * 8;
    int c = idx >> 6;
    int r = idx & 63;
    u16x8 v;
#pragma unroll
    for (int j = 0; j < 8; ++j) v[j] = f2bf(tile[r + j][c]);
    *(u16x8*)(out + (size_t)(c0 + c) * R + r0 + r) = v;
  }
}

// ---------------------------------------------------------------------------
// 128x128 bf16 GEMM main loop: C = A[M][K] * Bt[N][K]^T, BK=64.
// LDS tiles [128][64] bf16, XOR-swizzled rows (byte ^= (row&7)<<4).
// ---------------------------------------------------------------------------
__device__ __forceinline__ void gemm_tile_mainloop(
    const ushort_t* __restrict__ A, const ushort_t* __restrict__ Bt,
    const int K, const int m0, const int n0,
    ushort_t* aT, ushort_t* bT, f32x4 (&acc)[4][4]) {
  const int t = threadIdx.x;
  const int l = t & 63;
  const int wr = t >> 7;
  const int wc = (t >> 6) & 1;

#pragma unroll
  for (int mi = 0; mi < 4; ++mi)
#pragma unroll
    for (int ni = 0; ni < 4; ++ni) acc[mi][ni] = f32x4{0.f, 0.f, 0.f, 0.f};

  for (int k0 = 0; k0 < K; k0 += 64) {
#pragma unroll
    for (int c = 0; c < 4; ++c) {
      const int lin = c * 4096 + t * 16;
      const int row = lin >> 7;              // 128B rows
      const int scb = (lin & 127) ^ ((row & 7) << 4);   // inverse-swizzled src col
      const int ldso = (c * 4096 + (t >> 6) * 1024) >> 1; // wave-uniform elem offset
      gld_lds16(A + (size_t)(m0 + row) * K + k0 + (scb >> 1), aT + ldso);
      gld_lds16(Bt + (size_t)(n0 + row) * K + k0 + (scb >> 1), bT + ldso);
    }
    __syncthreads();
#pragma unroll
    for (int ks = 0; ks < 2; ++ks) {
      bf16x8 af[4], bfr[4];
#pragma unroll
      for (int mi = 0; mi < 4; ++mi) {
        const int row = wr * 64 + mi * 16 + (l & 15);
        const int cb = (((l >> 4) << 4) + (ks << 6)) ^ ((row & 7) << 4);
        af[mi] = *(const bf16x8*)((const char*)aT + row * 128 + cb);
      }
#pragma unroll
      for (int ni = 0; ni < 4; ++ni) {
        const int row = wc * 64 + ni * 16 + (l & 15);
        const int cb = (((l >> 4) << 4) + (ks << 6)) ^ ((row & 7) << 4);
        bfr[ni] = *(const bf16x8*)((const char*)bT + row * 128 + cb);
      }
#pragma unroll
      for (int mi = 0; mi < 4; ++mi)
#pragma unroll
        for (int ni = 0; ni < 4; ++ni)
          acc[mi][ni] = __builtin_amdgcn_mfma_f32_16x16x32_bf16(
              af[mi], bfr[ni], acc[mi][ni], 0, 0, 0);
    }
    __syncthreads();
  }
}

// QKV GEMM: writes Q,K as [b*h][tok][d] bf16 and V transposed [b*h][d][tok].
__global__ __launch_bounds__(256) void gemm_qkv_kernel(
    const ushort_t* __restrict__ xb, const ushort_t* __restrict__ wT,
    const float* __restrict__ bias,
    ushort_t* __restrict__ Qb, ushort_t* __restrict__ Kb, ushort_t* __restrict__ Vt) {
  __shared__ __align__(16) ushort_t aT[128 * 64];
  __shared__ __align__(16) ushort_t bT[128 * 64];
  f32x4 acc[4][4];
  const int m0 = blockIdx.y * 128, n0 = blockIdx.x * 128;
  gemm_tile_mainloop(xb, wT, DIN, m0, n0, aT, bT, acc);

  const int t = threadIdx.x, l = t & 63;
  const int wr = t >> 7, wc = (t >> 6) & 1;
  const int which = n0 >> 10;  // 0=q 1=k 2=v (128-tiles never straddle)
#pragma unroll
  for (int mi = 0; mi < 4; ++mi) {
#pragma unroll
    for (int ni = 0; ni < 4; ++ni) {
      const int n = n0 + wc * 64 + ni * 16 + (l & 15);
      const int h = (n >> 6) & 15, d = n & 63;
      const float bv = bias[n];
#pragma unroll
      for (int i = 0; i < 4; ++i) {
        const int m = m0 + wr * 64 + mi * 16 + ((l >> 4) << 2) + i;
        const int b = m >> 11, tok = m & 2047;
        const ushort_t val = f2bf(acc[mi][ni][i] + bv);
        const size_t bh = (size_t)((b << 4) + h);
        if (which == 0)      Qb[(bh * NTOK + tok) * HDIM + d] = val;
        else if (which == 1) Kb[(bh * NTOK + tok) * HDIM + d] = val;
        else                 Vt[(bh * HDIM + d) * NTOK + tok] = val;
      }
    }
  }
}

// proj GEMM: fp32 out + bias
__global__ __launch_bounds__(256) void gemm_proj_kernel(
    const ushort_t* __restrict__ ab, const ushort_t* __restrict__ wT,
    const float* __restrict__ bias, float* __restrict__ out) {
  __shared__ __align__(16) ushort_t aT[128 * 64];
  __shared__ __align__(16) ushort_t bT[128 * 64];
  f32x4 acc[4][4];
  const int m0 = blockIdx.y * 128, n0 = blockIdx.x * 128;
  gemm_tile_mainloop(ab, wT, DIN, m0, n0, aT, bT, acc);

  const int t = threadIdx.x, l = t & 63;
  const int wr = t >> 7, wc = (t >> 6) & 1;
#pragma unroll
  for (int mi = 0; mi < 4; ++mi) {
#pragma unroll
    for (int ni = 0; ni < 4; ++ni) {
      const int n = n0 + wc * 64 + ni * 16 + (l & 15);
      const float bv = bias[n];
#pragma unroll
      for (int i = 0; i < 4; ++i) {
        const int m = m0 + wr * 64 + mi * 16 + ((l >> 4) << 2) + i;
        out[(size_t)m * 1024 + n] = acc[mi][ni][i] + bv;
      }
    }
  }
}

// column-mean of V over all 2048 rows, per (b,h,d): one wave per output.
__global__ __launch_bounds__(256) void vmean_kernel(
    const ushort_t* __restrict__ Vt, ushort_t* __restrict__ vmean) {
  const int row = blockIdx.x * 4 + (threadIdx.x >> 6);  // 0..2047 = bh*64+d
  const int l = threadIdx.x & 63;
  const ushort_t* src = Vt + (size_t)row * NTOK;
  float s = 0.f;
#pragma unroll
  for (int j = 0; j < 4; ++j) {
    u16x8 v = *(const u16x8*)(src + ((j << 6) + l) * 8);
#pragma unroll
    for (int k = 0; k < 8; ++k) s += bf2f(v[k]);
  }
#pragma unroll
  for (int d2 = 1; d2 < 64; d2 <<= 1) s += __shfl_xor(s, d2);
  if (l == 0) vmean[row] = f2bf(s * (1.0f / 2048.0f));
}

// ---------------------------------------------------------------------------
// flash attention: QBLK=64 rows/block (4 waves x 16), KVBLK=128.
// valid rows: softmax over [0,valid). invalid rows: output = vmean.
// ---------------------------------------------------------------------------
__global__ __launch_bounds__(256) void attn_kernel(
    const ushort_t* __restrict__ Qb, const ushort_t* __restrict__ Kb,
    const ushort_t* __restrict__ Vt, const ushort_t* __restrict__ vmean,
    const int* __restrict__ validp, ushort_t* __restrict__ ob) {
  __shared__ __align__(16) ushort_t kT[128 * 64];    // [kv][d] swizzled
  __shared__ __align__(16) ushort_t vT[64 * 128];    // [d][kv] swizzled
  __shared__ __align__(16) ushort_t pT[4][16 * 128]; // per-wave [q][kv] swizzled

  const int qt = blockIdx.x, h = blockIdx.y, b = blockIdx.z;
  const int q0 = qt << 6;
  const int valid = validp[b];
  const int t = threadIdx.x, w = t >> 6, l = t & 63;
  const size_t bh = (size_t)((b << 4) + h);
  const ushort_t* Qp = Qb + bh * (NTOK * HDIM);
  const ushort_t* Kp = Kb + bh * (NTOK * HDIM);
  const ushort_t* Vp = Vt + bh * (HDIM * NTOK);

  // Q fragments for this wave's 16 rows (hoisted; global, coalesced 16B)
  bf16x8 qf[2];
  {
    const int row = q0 + w * 16 + (l & 15);
    const ushort_t* s0 = Qp + (size_t)row * HDIM + ((l >> 4) << 3);
    qf[0] = *(const bf16x8*)(s0);
    qf[1] = *(const bf16x8*)(s0 + 32);
  }

  float mrow[4], lsum[4];
  f32x4 oacc[4];
#pragma unroll
  for (int i = 0; i < 4; ++i) { mrow[i] = -INFINITY; lsum[i] = 0.f; oacc[i] = f32x4{0.f,0.f,0.f,0.f}; }

  const int vlimit = (q0 < valid) ? valid : 0;
  for (int kv0 = 0; kv0 < vlimit; kv0 += 128) {
#pragma unroll
    for (int c = 0; c < 4; ++c) {
      const int lin = c * 4096 + t * 16;
      const int ldso = (c * 4096 + (t >> 6) * 1024) >> 1;
      {  // K tile [128][64], 128B rows
        const int row = lin >> 7;
        const int scb = (lin & 127) ^ ((row & 7) << 4);
        gld_lds16(Kp + (size_t)(kv0 + row) * HDIM + (scb >> 1), kT + ldso);
      }
      {  // V^T tile [64][128], 256B rows
        const int row = lin >> 8;
        const int scb = (lin & 255) ^ ((row & 7) << 4);
        gld_lds16(Vp + (size_t)row * NTOK + kv0 + (scb >> 1), vT + ldso);
      }
    }
    __syncthreads();

    // S = Q K^T  (8 col-blocks of 16)
    f32x4 s[8];
#pragma unroll
    for (int blk = 0; blk < 8; ++blk) s[blk] = f32x4{0.f,0.f,0.f,0.f};
#pragma unroll
    for (int ks = 0; ks < 2; ++ks) {
#pragma unroll
      for (int blk = 0; blk < 8; ++blk) {
        const int kr = (blk << 4) + (l & 15);
        const int cb = (((l >> 4) << 4) + (ks << 6)) ^ ((kr & 7) << 4);
        bf16x8 kf = *(const bf16x8*)((const char*)kT + kr * 128 + cb);
        s[blk] = __builtin_amdgcn_mfma_f32_16x16x32_bf16(qf[ks], kf, s[blk], 0, 0, 0);
      }
    }

    // scale + column mask + row max
    float tmax[4];
#pragma unroll
    for (int i = 0; i < 4; ++i) tmax[i] = -1e30f;
#pragma unroll
    for (int blk = 0; blk < 8; ++blk) {
      const int col = kv0 + (blk << 4) + (l & 15);
      const bool ok = col < valid;
#pragma unroll
      for (int i = 0; i < 4; ++i) {
        float v = ok ? s[blk][i] * 0.125f : -1e30f;
        s[blk][i] = v;
        tmax[i] = fmaxf(tmax[i], v);
      }
    }
#pragma unroll
    for (int d2 = 1; d2 < 16; d2 <<= 1)
#pragma unroll
      for (int i = 0; i < 4; ++i) tmax[i] = fmaxf(tmax[i], __shfl_xor(tmax[i], d2));

    float mnew[4], rescale[4], tsum[4];
#pragma unroll
    for (int i = 0; i < 4; ++i) {
      mnew[i] = fmaxf(mrow[i], tmax[i]);
      rescale[i] = __expf(mrow[i] - mnew[i]);  // exp(-inf)=0 on first tile
      tsum[i] = 0.f;
    }

    // P = exp(S - m), staged to per-wave swizzled LDS (C-layout -> A-layout)
#pragma unroll
    for (int blk = 0; blk < 8; ++blk) {
#pragma unroll
      for (int i = 0; i < 4; ++i) {
        const float p = __expf(s[blk][i] - mnew[i]);
        tsum[i] += p;
        const int pr = ((l >> 4) << 2) + i;
        const int cb = (((blk << 4) + (l & 15)) << 1) ^ ((pr & 7) << 4);
        *(ushort_t*)((char*)pT[w] + pr * 256 + cb) = f2bf(p);
      }
    }
#pragma unroll
    for (int d2 = 1; d2 < 16; d2 <<= 1)
#pragma unroll
      for (int i = 0; i < 4; ++i) tsum[i] += __shfl_xor(tsum[i], d2);
#pragma unroll
    for (int i = 0; i < 4; ++i) {
      lsum[i] = lsum[i] * rescale[i] + tsum[i];
      mrow[i] = mnew[i];
    }
#pragma unroll
    for (int dblk = 0; dblk < 4; ++dblk)
#pragma unroll
      for (int i = 0; i < 4; ++i) oacc[dblk][i] *= rescale[i];

    // O += P V   (P from wave-private LDS, V^T from shared LDS)
#pragma unroll
    for (int ks = 0; ks < 4; ++ks) {
      const int pr = l & 15;
      const int cba = (((l >> 4) << 4) + (ks << 6)) ^ ((pr & 7) << 4);
      bf16x8 pf = *(const bf16x8*)((const char*)pT[w] + pr * 256 + cba);
#pragma unroll
      for (int dblk = 0; dblk < 4; ++dblk) {
        const int vr = (dblk << 4) + (l & 15);
        const int cbb = (((l >> 4) << 4) + (ks << 6)) ^ ((vr & 7) << 4);
        bf16x8 vf = *(const bf16x8*)((const char*)vT + vr * 256 + cbb);
        oacc[dblk] = __builtin_amdgcn_mfma_f32_16x16x32_bf16(pf, vf, oacc[dblk], 0, 0, 0);
      }
    }
    __syncthreads();
  }

  // write valid rows
  if (q0 < valid) {
#pragma unroll
    for (int dblk = 0; dblk < 4; ++dblk) {
#pragma unroll
      for (int i = 0; i < 4; ++i) {
        const int row = q0 + w * 16 + ((l >> 4) << 2) + i;
        if (row < valid) {
          const int d = (dblk << 4) + (l & 15);
          ob[((size_t)(b * NTOK) + row) * 1024 + (h << 6) + d] =
              f2bf(oacc[dblk][i] / lsum[i]);
        }
      }
    }
  }
  // invalid rows: uniform softmax over ALL tokens -> column mean of V
  for (int it = 0; it < 16; ++it) {
    const int idx = it * 256 + t;
    const int row = q0 + (idx >> 6);
    if (row >= valid) {
      const int d = idx & 63;
      ob[((size_t)(b * NTOK) + row) * 1024 + (h << 6) + d] = vmean[(bh << 6) + d];
    }
  }
}

// ---------------------------------------------------------------------------
extern "C" void kernel_launch(void* const* d_in, const int* in_sizes, int n_in,
                              void* d_out, int out_size, void* d_ws, size_t ws_size,
                              hipStream_t stream) {
  (void)in_sizes; (void)n_in; (void)out_size; (void)ws_size;
  const float* x      = (const float*)d_in[0];
  const int*   validp = (const int*)d_in[1];
  const float* W_qkv  = (const float*)d_in[2];
  const float* b_qkv  = (const float*)d_in[3];
  const float* W_proj = (const float*)d_in[4];
  const float* b_proj = (const float*)d_in[5];
  float* out = (float*)d_out;

  ushort_t* xb     = (ushort_t*)d_ws;        // 4194304 elems (x bf16)
  ushort_t* wqkvT  = xb + 4194304;           // 3145728  (W_qkv^T bf16 [3072][1024])
  ushort_t* wprojT = wqkvT + 3145728;        // 1048576  (W_proj^T bf16 [1024][1024])
  ushort_t* Qb     = wprojT + 1048576;       // 4194304  ([b*h][tok][d])
  ushort_t* Kb     = Qb + 4194304;           // 4194304
  ushort_t* Vt     = Kb + 4194304;           // 4194304  ([b*h][d][tok])
  ushort_t* ab     = Vt + 4194304;           // 4194304  (attn out bf16 [m][1024])
  ushort_t* vm     = ab + 4194304;           // 2048     (vmean bf16)

  conv_bf16_kernel<<<2048, 256, 0, stream>>>(x, xb, 4194304);
  transpose_bf16_kernel<<<dim3(48, 16), 256, 0, stream>>>(W_qkv, wqkvT, 1024, 3072);
  transpose_bf16_kernel<<<dim3(16, 16), 256, 0, stream>>>(W_proj, wprojT, 1024, 1024);
  gemm_qkv_kernel<<<dim3(24, 32), 256, 0, stream>>>(xb, wqkvT, b_qkv, Qb, Kb, Vt);
  vmean_kernel<<<512, 256, 0, stream>>>(Vt, vm);
  attn_kernel<<<dim3(32, 16, 2), 256, 0, stream>>>(Qb, Kb, Vt, vm, validp, ab);
  gemm_proj_kernel<<<dim3(8, 32), 256, 0, stream>>>(ab, wprojT, b_proj, out);
}